// Round 4
// baseline (241.834 us; speedup 1.0000x reference)
//
#include <hip/hip_runtime.h>

#define EPS 1e-5f

typedef float v2f __attribute__((ext_vector_type(2)));

__device__ __forceinline__ float ht(float x){ return fminf(fmaxf(x, -1.f), 1.f); }
__device__ __forceinline__ float sgn(float v){ return (v > 0.f) ? 1.f : ((v < 0.f) ? -1.f : 0.f); }
__device__ __forceinline__ v2f pkfma(v2f a, v2f b, v2f c){ return __builtin_elementwise_fma(a, b, c); }

// ---------------- Kernel 1: conv1(K=17,s=2,p=8) + BN + hardtanh + maxpool2 ----------------
// x[B,16384] -> out1[B,16,4096].  512 thr; packed-fp32 FMA over k-pairs (wsh rows padded to 18).
__global__ __launch_bounds__(512, 6) void k1(const float* __restrict__ x,
        const float* __restrict__ w1, const float* __restrict__ g1,
        const float* __restrict__ b1, const float* __restrict__ m1,
        const float* __restrict__ v1, float* __restrict__ out1){
    __shared__ __align__(16) float xs[2064];
    __shared__ __align__(16) float wsh[16*18];     // rows padded to 18, [17]=0
    __shared__ float sc[16], sh[16];
    const int b   = blockIdx.x >> 3;          // 8 tiles of 512 pooled per b
    const int p0  = (blockIdx.x & 7) * 512;
    const int tid = threadIdx.x;
    const int base = 4*p0 - 8;                // x index of LDS slot 0 (16B aligned)
    const float* xrow = &x[b*16384];
    for(int i = tid; i < 516; i += 512){
        int g0 = base + 4*i;
        float4 v = make_float4(0.f,0.f,0.f,0.f);
        if(g0 >= 0 && g0 <= 16380) v = *(const float4*)&xrow[g0];  // full-in or full-out
        *(float4*)&xs[4*i] = v;
    }
    if(tid < 288){
        int oc = tid / 18, k = tid - oc*18;
        wsh[tid] = (k < 17) ? w1[oc*17 + k] : 0.f;
    }
    if(tid < 16){
        float s = g1[tid] * rsqrtf(v1[tid] + EPS);
        sc[tid] = s; sh[tid] = b1[tid] - m1[tid]*s;
    }
    __syncthreads();
    const int oc = tid & 15;                  // FAST lane: oc (broadcast x reads)
    v2f wv2[9];
    #pragma unroll
    for(int p = 0; p < 9; ++p) wv2[p] = *(const v2f*)&wsh[oc*18 + 2*p];
    const float s = sc[oc], h = sh[oc];
    #pragma unroll
    for(int it = 0; it < 4; ++it){
        int gq = (tid >> 4) + it*32;          // 0..127 pooled quad
        v2f xr2[16];
        #pragma unroll
        for(int i = 0; i < 16; ++i)
            xr2[i] = *(const v2f*)&xs[16*gq + 2*i];
        float4 o; float* op = &o.x;
        #pragma unroll
        for(int j = 0; j < 4; ++j){
            v2f a0 = {0.f,0.f}, a1 = {0.f,0.f};
            #pragma unroll
            for(int p = 0; p < 9; ++p){
                a0 = pkfma(wv2[p], xr2[2*j + p],     a0);
                a1 = pkfma(wv2[p], xr2[2*j + 1 + p], a1);
            }
            float r0 = a0.x + a0.y, r1 = a1.x + a1.y;
            op[j] = fmaxf(ht(r0*s + h), ht(r1*s + h));
        }
        *(float4*)&out1[(b*16 + oc)*4096 + p0 + 4*gq] = o;
    }
}

// ---------------- Kernel 2: conv2(sign w, K=9,s=2,p=4) + BN + hardtanh + maxpool2 --------
// out1[B,16,4096] -> out2[B,32,1024].  Weights as [ic][kpair(5)][oc(32)] float2 (pair k=8 padded
// with 0) -> one b128 per (ic,p) fetches both ocs' pair, lane-coalesced, conflict-free.
__global__ __launch_bounds__(512, 6) void k2(const float* __restrict__ in,
        const float* __restrict__ w2, const float* __restrict__ g2,
        const float* __restrict__ be2, const float* __restrict__ m2,
        const float* __restrict__ v2, float* __restrict__ out2){
    __shared__ __align__(16) float a[16*520];       // row j holds in[4*p0-4+j]
    __shared__ __align__(16) v2f  wp2[16*5*32];     // (ic*5+p)*32 + oc
    __shared__ float sc[32], sh[32];
    const int b   = blockIdx.x >> 3;                // 8 tiles of 128 pooled per b
    const int p0  = (blockIdx.x & 7) * 128;
    const int tid = threadIdx.x;
    const int base = 4*p0 - 4;                      // 16B aligned
    for(int i = tid; i < 2080; i += 512){           // 16 rows x 130 float4
        int row = i / 130, m = i - row*130;
        int g0  = base + 4*m;
        float4 v = make_float4(0.f,0.f,0.f,0.f);
        if(g0 >= 0 && g0 <= 4092) v = *(const float4*)&in[(b*16 + row)*4096 + g0];
        *(float4*)&a[row*520 + 4*m] = v;
    }
    for(int i = tid; i < 2560; i += 512){           // 16 ic x 5 pairs x 32 oc
        int oc = i & 31, t = i >> 5;                // t = ic*5+p
        int p  = t % 5, ic = t / 5;
        int gbase = oc*144 + ic*9 + 2*p;
        v2f w; w.x = sgn(w2[gbase]); w.y = (2*p+1 < 9) ? sgn(w2[gbase+1]) : 0.f;
        wp2[i] = w;
    }
    if(tid < 32){
        float s = g2[tid] * rsqrtf(v2[tid] + EPS);
        sc[tid] = s; sh[tid] = be2[tid] - m2[tid]*s;
    }
    __syncthreads();
    const int ocp = tid & 15;                       // FAST: oc pair
    const int g   = tid >> 4;                       // SLOW: pooled quad, 0..31
    const int oc0 = 2*ocp;
    v2f acc2[2][4][2] = {};                         // [oc][j][poolhalf], lanes = k-pair
    for(int ic = 0; ic < 16; ++ic){
        v2f xr2[12];
        #pragma unroll
        for(int i = 0; i < 12; ++i)
            xr2[i] = *(const v2f*)&a[ic*520 + 16*g + 2*i];
        const v2f* wrow = &wp2[ic*5*32];
        #pragma unroll
        for(int p = 0; p < 5; ++p){
            v2f w0 = wrow[p*32 + oc0];
            v2f w1v = wrow[p*32 + oc0 + 1];
            #pragma unroll
            for(int j = 0; j < 4; ++j){
                #pragma unroll
                for(int hh = 0; hh < 2; ++hh){
                    v2f xv = xr2[2*j + hh + p];
                    acc2[0][j][hh] = pkfma(w0,  xv, acc2[0][j][hh]);
                    acc2[1][j][hh] = pkfma(w1v, xv, acc2[1][j][hh]);
                }
            }
        }
    }
    #pragma unroll
    for(int o = 0; o < 2; ++o){
        int oc = oc0 + o;
        float s = sc[oc], h = sh[oc];
        float4 y; float* yp = &y.x;
        #pragma unroll
        for(int j = 0; j < 4; ++j){
            float r0 = acc2[o][j][0].x + acc2[o][j][0].y;
            float r1 = acc2[o][j][1].x + acc2[o][j][1].y;
            yp[j] = fmaxf(ht(r0*s + h), ht(r1*s + h));
        }
        *(float4*)&out2[(b*32 + oc)*1024 + p0 + 4*g] = y;
    }
}

// ---------------- Kernel 3: conv3(sign w, K=5,s=2,p=2) + BN + hardtanh + maxpool2 --------
// out2[B,32,1024] -> out3[B,64,256].  32-oc halves per block; weights [ic][kpair(3)][oc(32)]
// float2 (k=5 pad 0); thread = ocpair x pooled-pair, pk-FMA.
__global__ __launch_bounds__(512, 4) void k3(const float* __restrict__ in,
        const float* __restrict__ w3, const float* __restrict__ g3,
        const float* __restrict__ be3, const float* __restrict__ m3,
        const float* __restrict__ v3, float* __restrict__ out3){
    __shared__ __align__(16) float a[32*264];       // row j holds in[4*p0-4+j], 262 used
    __shared__ __align__(16) v2f  wp3[32*3*32];     // (ic*3+p)*32 + ocl
    __shared__ float sc[32], sh[32];
    const int b      = blockIdx.x >> 3;
    const int rem    = blockIdx.x & 7;
    const int p0     = (rem & 3) * 64;
    const int ocbase = (rem >> 2) * 32;
    const int tid = threadIdx.x;
    const int base = 4*p0 - 4;                      // 16B aligned
    for(int i = tid; i < 2112; i += 512){           // 32 rows x 66 float4
        int row = i / 66, m = i - row*66;
        int g0  = base + 4*m;
        float4 v = make_float4(0.f,0.f,0.f,0.f);
        if(g0 >= 0 && g0 <= 1020) v = *(const float4*)&in[(b*32 + row)*1024 + g0];
        *(float4*)&a[row*264 + 4*m] = v;
    }
    for(int i = tid; i < 3072; i += 512){           // 32 ic x 3 pairs x 32 ocl
        int ocl = i & 31, t = i >> 5;               // t = ic*3+p
        int p   = t % 3, ic = t / 3;
        int gbase = (ocbase + ocl)*160 + ic*5 + 2*p;
        v2f w; w.x = sgn(w3[gbase]); w.y = (2*p+1 < 5) ? sgn(w3[gbase+1]) : 0.f;
        wp3[i] = w;
    }
    if(tid < 32){
        int c = ocbase + tid;
        float s = g3[c] * rsqrtf(v3[c] + EPS);
        sc[tid] = s; sh[tid] = be3[c] - m3[c]*s;
    }
    __syncthreads();
    const int ocp = tid & 15;                       // FAST: oc pair (32 oc)
    const int hq  = tid >> 4;                       // SLOW: pooled pair, 0..31
    const int oc0 = 2*ocp;
    v2f acc2[2][2][2] = {};                         // [oc][q][poolhalf]
    for(int ic = 0; ic < 32; ++ic){
        v2f xr2[6];                                 // floats a[ic*264 + 8hq + 2..13]
        #pragma unroll
        for(int i = 0; i < 6; ++i)
            xr2[i] = *(const v2f*)&a[ic*264 + 8*hq + 2 + 2*i];
        const v2f* wrow = &wp3[ic*3*32];
        #pragma unroll
        for(int p = 0; p < 3; ++p){
            v2f w0 = wrow[p*32 + oc0];
            v2f w1v = wrow[p*32 + oc0 + 1];
            #pragma unroll
            for(int q = 0; q < 2; ++q){
                #pragma unroll
                for(int hh = 0; hh < 2; ++hh){
                    v2f xv = xr2[2*q + hh + p];     // float offset 4q+2h+2+2p - 2
                    acc2[0][q][hh] = pkfma(w0,  xv, acc2[0][q][hh]);
                    acc2[1][q][hh] = pkfma(w1v, xv, acc2[1][q][hh]);
                }
            }
        }
    }
    #pragma unroll
    for(int o = 0; o < 2; ++o){
        int oc = oc0 + o;
        float s = sc[oc], h = sh[oc];
        v2f y;
        #pragma unroll
        for(int q = 0; q < 2; ++q){
            float r0 = acc2[o][q][0].x + acc2[o][q][0].y;
            float r1 = acc2[o][q][1].x + acc2[o][q][1].y;
            y[q] = fmaxf(ht(r0*s + h), ht(r1*s + h));
        }
        *(v2f*)&out3[(b*64 + ocbase + oc)*256 + p0 + 2*hq] = y;
    }
}

// ---------------- Kernel 4: mean over L + concat rms + fc1 + hardtanh + fc2 --------------
// out3[B,64,256] -> out[B,2]
__global__ __launch_bounds__(256) void k4(const float* __restrict__ p3,
        const float* __restrict__ rms, const float* __restrict__ fc1w,
        const float* __restrict__ fc1b, const float* __restrict__ fc2w,
        const float* __restrict__ fc2b, float* __restrict__ out){
    __shared__ float part[256];
    __shared__ float feat[64];
    __shared__ float hbuf[32];
    const int b = blockIdx.x;
    const int tid = threadIdx.x;
    const int oc = tid >> 2, q = tid & 3;
    const float* row = &p3[(b*64 + oc)*256 + q*64];
    float s = 0.f;
    for(int j = 0; j < 16; ++j){
        float4 v = *(const float4*)&row[4*j];
        s += v.x + v.y + v.z + v.w;
    }
    part[tid] = s;
    __syncthreads();
    if(tid < 64)
        feat[tid] = (part[4*tid] + part[4*tid+1] + part[4*tid+2] + part[4*tid+3]) * (1.f/256.f);
    __syncthreads();
    if(tid < 32){
        float acc = fc1b[tid];
        const float* w = &fc1w[tid*65];
        #pragma unroll
        for(int c = 0; c < 64; ++c) acc += w[c]*feat[c];
        acc += w[64]*rms[b];
        hbuf[tid] = ht(acc);
    }
    __syncthreads();
    if(tid < 2){
        float acc = fc2b[tid];
        const float* w = &fc2w[tid*32];
        #pragma unroll
        for(int j = 0; j < 32; ++j) acc += w[j]*hbuf[j];
        out[b*2 + tid] = acc;
    }
}

extern "C" void kernel_launch(void* const* d_in, const int* in_sizes, int n_in,
                              void* d_out, int out_size, void* d_ws, size_t ws_size,
                              hipStream_t stream){
    (void)in_sizes; (void)n_in; (void)out_size; (void)ws_size;
    const float* x    = (const float*)d_in[0];
    const float* rms  = (const float*)d_in[1];
    const float* w1   = (const float*)d_in[2];
    const float* g1   = (const float*)d_in[3];
    const float* b1   = (const float*)d_in[4];
    const float* m1   = (const float*)d_in[5];
    const float* v1   = (const float*)d_in[6];
    const float* w2   = (const float*)d_in[7];
    const float* g2   = (const float*)d_in[8];
    const float* b2   = (const float*)d_in[9];
    const float* m2   = (const float*)d_in[10];
    const float* v2   = (const float*)d_in[11];
    const float* w3   = (const float*)d_in[12];
    const float* g3   = (const float*)d_in[13];
    const float* b3   = (const float*)d_in[14];
    const float* m3   = (const float*)d_in[15];
    const float* v3   = (const float*)d_in[16];
    const float* fc1w = (const float*)d_in[17];
    const float* fc1b = (const float*)d_in[18];
    const float* fc2w = (const float*)d_in[19];
    const float* fc2b = (const float*)d_in[20];
    float* out  = (float*)d_out;

    float* out1 = (float*)d_ws;                 // 256*16*4096 = 16,777,216 floats
    float* out2 = out1 + 256*16*4096;           // 256*32*1024 =  8,388,608 floats
    float* out3 = out2 + 256*32*1024;           // 256*64*256  =  4,194,304 floats

    k1<<<2048, 512, 0, stream>>>(x,    w1, g1, b1, m1, v1, out1);
    k2<<<2048, 512, 0, stream>>>(out1, w2, g2, b2, m2, v2, out2);
    k3<<<2048, 512, 0, stream>>>(out2, w3, g3, b3, m3, v3, out3);
    k4<<<256,  256, 0, stream>>>(out3, rms, fc1w, fc1b, fc2w, fc2b, out);
}

// Round 5
// 159.620 us; speedup vs baseline: 1.5151x; 1.5151x over previous
//
#include <hip/hip_runtime.h>

#define EPS 1e-5f

typedef float f32x4 __attribute__((ext_vector_type(4)));
typedef short s16x8 __attribute__((ext_vector_type(8)));

union FragU { uint4 u; s16x8 s; };

__device__ __forceinline__ float ht(float x){ return fminf(fmaxf(x,-1.f),1.f); }
__device__ __forceinline__ float sgn(float v){ return (v>0.f)?1.f:((v<0.f)?-1.f:0.f); }
__device__ __forceinline__ unsigned short f2bf(float f){
    unsigned int u = __builtin_bit_cast(unsigned int, f);
    u += 0x7FFFu + ((u>>16)&1u);                 // RNE to bf16
    return (unsigned short)(u>>16);
}

// =============== prep: A-fragments (bf16, MFMA layout) + BN scale/shift ===============
// A-frag layout per shape 16x16x32: lane(m=lane&15,q=lane>>4) holds A[m][8q+j], j=0..7.
// K-ordering (k-major): conv1 r=k (Cin=1); conv2 r=k*16+ic (k padded 9->10, K=160);
// conv3 r=k*32+ic (K=160 exact, 5 chunks of 32 = one k each).
__global__ __launch_bounds__(512) void prep(
    const float* __restrict__ w1, const float* __restrict__ w2, const float* __restrict__ w3,
    const float* g1,const float* b1,const float* m1,const float* v1,
    const float* g2,const float* b2,const float* m2,const float* v2,
    const float* g3,const float* b3,const float* m3,const float* v3,
    unsigned short* __restrict__ a1, unsigned short* __restrict__ a2,
    unsigned short* __restrict__ a3, float* __restrict__ bn){
  const int t = threadIdx.x;
  if(t < 64){                                    // conv1: 1 chunk (K=32, k<17 real)
    int q = t>>4, m = t&15;
    #pragma unroll
    for(int j=0;j<8;++j){ int k = 8*q+j;
      a1[t*8+j] = f2bf((k<17)? w1[m*17+k] : 0.f); }
  }
  for(int e = t; e < 640; e += 512){             // conv2: [h2][c5][q4][m16]
    int m = e&15, q = (e>>4)&3, hc = e>>6, c = hc%5, h = hc/5;
    int oc = m + 16*h, k = 2*c + (q>>1);
    #pragma unroll
    for(int j=0;j<8;++j){ int ic = 8*(q&1)+j;
      a2[e*8+j] = f2bf((k<9)? sgn(w2[(oc*16+ic)*9+k]) : 0.f); }
  }
  for(int e = t; e < 1280; e += 512){            // conv3: [h4][c5][q4][m16]
    int m = e&15, q = (e>>4)&3, hc = e>>6, c = hc%5, h = hc/5;
    int oc = m + 16*h;
    #pragma unroll
    for(int j=0;j<8;++j){ int ic = 8*q+j;
      a3[e*8+j] = f2bf(sgn(w3[(oc*32+ic)*5+c])); }
  }
  if(t<16){ float s = g1[t]*rsqrtf(v1[t]+EPS); bn[t]    = s; bn[16+t]  = b1[t]-m1[t]*s; }
  if(t<32){ float s = g2[t]*rsqrtf(v2[t]+EPS); bn[32+t] = s; bn[64+t]  = b2[t]-m2[t]*s; }
  if(t<64){ float s = g3[t]*rsqrtf(v3[t]+EPS); bn[96+t] = s; bn[160+t] = b3[t]-m3[t]*s; }
}

// =============== k1: conv1 MFMA + BN + ht + pool -> out1T[b][pp4096][ic16] bf16 ===========
__global__ __launch_bounds__(512) void k1(const float* __restrict__ x,
    const unsigned short* __restrict__ a1, const float* __restrict__ bn,
    unsigned short* __restrict__ out1T){
  __shared__ unsigned short xs[1056];            // x[2N0-8 .. +1047] in bf16
  const int b  = blockIdx.x >> 4;
  const int N0 = (blockIdx.x & 15) * 512;        // pre-pool base (512 per block)
  const int tid = threadIdx.x;
  const float* xrow = &x[b*16384];
  for(int i = tid; i < 1056; i += 512){
    int xg = 2*N0 - 8 + i;
    xs[i] = f2bf((xg>=0 && xg<16384)? xrow[xg] : 0.f);
  }
  const int lane = tid & 63, m = lane & 15, q = lane >> 4, w = tid >> 6;
  FragU af; af.u = *(const uint4*)&a1[(q*16+m)*8];
  const float4 scv = *(const float4*)&bn[4*q];
  const float4 shv = *(const float4*)&bn[16+4*q];
  __syncthreads();
  const unsigned int* X32 = (const unsigned int*)xs;
  #pragma unroll
  for(int it=0; it<4; ++it){
    int nloc = (it*8 + w)*16 + m;                // local pre-pool position = column
    int d = nloc + 4*q;                          // dword idx of B-frag start
    FragU bf;
    bf.u.x = X32[d]; bf.u.y = X32[d+1]; bf.u.z = X32[d+2]; bf.u.w = X32[d+3];
    f32x4 acc = {0.f,0.f,0.f,0.f};
    acc = __builtin_amdgcn_mfma_f32_16x16x32_bf16(af.s, bf.s, acc, 0,0,0);
    float r0 = ht(acc[0]*scv.x + shv.x);
    float r1 = ht(acc[1]*scv.y + shv.y);
    float r2 = ht(acc[2]*scv.z + shv.z);
    float r3 = ht(acc[3]*scv.w + shv.w);
    float p0 = fmaxf(r0, __shfl_xor(r0,1,64));
    float p1 = fmaxf(r1, __shfl_xor(r1,1,64));
    float p2 = fmaxf(r2, __shfl_xor(r2,1,64));
    float p3 = fmaxf(r3, __shfl_xor(r3,1,64));
    if((m&1)==0){
      int pp = (N0 + nloc) >> 1;
      uint2 pk;
      pk.x = (unsigned int)f2bf(p0) | ((unsigned int)f2bf(p1)<<16);
      pk.y = (unsigned int)f2bf(p2) | ((unsigned int)f2bf(p3)<<16);
      *(uint2*)&out1T[(b*4096 + pp)*16 + 4*q] = pk;    // transposed store [pp][oc]
    }
  }
}

// =============== k2: conv2 MFMA + BN + ht + pool -> out2T[b][pp1024][ic32] bf16 ===========
__global__ __launch_bounds__(512) void k2(const unsigned short* __restrict__ in,
    const unsigned short* __restrict__ a2, const float* __restrict__ bn,
    unsigned short* __restrict__ out2T){
  __shared__ unsigned short xs[520*24];          // rows padded 32B->48B (bank spread)
  const int b  = blockIdx.x >> 3;
  const int N0 = (blockIdx.x & 7) * 256;         // pre-pool base
  const int tid = threadIdx.x;
  const int pos0 = 2*N0 - 4;
  for(int e = tid; e < 1040; e += 512){          // 520 rows x 2 granules(16B)
    int row = e >> 1, half = e & 1;
    int pos = pos0 + row;
    uint4 v = make_uint4(0,0,0,0);
    if(pos>=0 && pos<4096) v = *(const uint4*)&in[(b*4096 + pos)*16 + 8*half];
    *(uint4*)&xs[row*24 + 8*half] = v;
  }
  const int lane = tid & 63, m = lane & 15, q = lane >> 4, w = tid >> 6;
  FragU af[2][5];
  #pragma unroll
  for(int h=0;h<2;++h)
    #pragma unroll
    for(int c=0;c<5;++c)
      af[h][c].u = *(const uint4*)&a2[(((h*5+c)*4+q)*16+m)*8];
  float4 scv[2], shv[2];
  #pragma unroll
  for(int h=0;h<2;++h){
    scv[h] = *(const float4*)&bn[32 + 16*h + 4*q];
    shv[h] = *(const float4*)&bn[64 + 16*h + 4*q];
  }
  __syncthreads();
  #pragma unroll
  for(int it=0; it<2; ++it){
    int nloc = (it*8 + w)*16 + m;
    f32x4 acc[2] = {{0.f,0.f,0.f,0.f},{0.f,0.f,0.f,0.f}};
    #pragma unroll
    for(int c=0;c<5;++c){                        // chunk c: k = 2c + (q>>1)
      int row = 2*nloc + 2*c + (q>>1);
      FragU bf; bf.u = *(const uint4*)&xs[row*24 + 8*(q&1)];
      acc[0] = __builtin_amdgcn_mfma_f32_16x16x32_bf16(af[0][c].s, bf.s, acc[0],0,0,0);
      acc[1] = __builtin_amdgcn_mfma_f32_16x16x32_bf16(af[1][c].s, bf.s, acc[1],0,0,0);
    }
    int pp = (N0 + nloc) >> 1;
    #pragma unroll
    for(int h=0;h<2;++h){
      float r0 = ht(acc[h][0]*scv[h].x + shv[h].x);
      float r1 = ht(acc[h][1]*scv[h].y + shv[h].y);
      float r2 = ht(acc[h][2]*scv[h].z + shv[h].z);
      float r3 = ht(acc[h][3]*scv[h].w + shv[h].w);
      float p0 = fmaxf(r0, __shfl_xor(r0,1,64));
      float p1 = fmaxf(r1, __shfl_xor(r1,1,64));
      float p2 = fmaxf(r2, __shfl_xor(r2,1,64));
      float p3 = fmaxf(r3, __shfl_xor(r3,1,64));
      if((m&1)==0){
        uint2 pk;
        pk.x = (unsigned int)f2bf(p0) | ((unsigned int)f2bf(p1)<<16);
        pk.y = (unsigned int)f2bf(p2) | ((unsigned int)f2bf(p3)<<16);
        *(uint2*)&out2T[(b*1024 + pp)*32 + 16*h + 4*q] = pk;
      }
    }
  }
}

// =============== k3: conv3 MFMA + BN + ht + pool -> out3[b][pp256][oc64] f32 ==============
__global__ __launch_bounds__(512) void k3(const unsigned short* __restrict__ in,
    const unsigned short* __restrict__ a3, const float* __restrict__ bn,
    float* __restrict__ out3){
  __shared__ unsigned short xs[520*40];          // rows padded 64B->80B
  const int b   = blockIdx.x >> 2;
  const int N0  = ((blockIdx.x>>1) & 1) * 256;   // pre-pool base (512 total per b)
  const int hb  = blockIdx.x & 1;                // oc half: 0->oc0..31, 1->oc32..63
  const int tid = threadIdx.x;
  const int pos0 = 2*N0 - 2;
  for(int e = tid; e < 2080; e += 512){          // 520 rows x 4 granules(16B)
    int row = e >> 2, g4 = e & 3;
    int pos = pos0 + row;
    uint4 v = make_uint4(0,0,0,0);
    if(pos>=0 && pos<1024) v = *(const uint4*)&in[(b*1024 + pos)*32 + 8*g4];
    *(uint4*)&xs[row*40 + 8*g4] = v;
  }
  const int lane = tid & 63, m = lane & 15, q = lane >> 4, w = tid >> 6;
  FragU af[2][5];
  #pragma unroll
  for(int h=0;h<2;++h)
    #pragma unroll
    for(int c=0;c<5;++c)
      af[h][c].u = *(const uint4*)&a3[((((2*hb+h)*5+c)*4+q)*16+m)*8];
  float4 scv[2], shv[2];
  #pragma unroll
  for(int h=0;h<2;++h){
    scv[h] = *(const float4*)&bn[96  + 32*hb + 16*h + 4*q];
    shv[h] = *(const float4*)&bn[160 + 32*hb + 16*h + 4*q];
  }
  __syncthreads();
  #pragma unroll
  for(int it=0; it<2; ++it){
    int nloc = (it*8 + w)*16 + m;
    f32x4 acc[2] = {{0.f,0.f,0.f,0.f},{0.f,0.f,0.f,0.f}};
    #pragma unroll
    for(int c=0;c<5;++c){                        // chunk c: k = c, ic = 8q+j
      int row = 2*nloc + c;
      FragU bf; bf.u = *(const uint4*)&xs[row*40 + 8*q];
      acc[0] = __builtin_amdgcn_mfma_f32_16x16x32_bf16(af[0][c].s, bf.s, acc[0],0,0,0);
      acc[1] = __builtin_amdgcn_mfma_f32_16x16x32_bf16(af[1][c].s, bf.s, acc[1],0,0,0);
    }
    int pp = (N0 + nloc) >> 1;
    #pragma unroll
    for(int h=0;h<2;++h){
      float r0 = ht(acc[h][0]*scv[h].x + shv[h].x);
      float r1 = ht(acc[h][1]*scv[h].y + shv[h].y);
      float r2 = ht(acc[h][2]*scv[h].z + shv[h].z);
      float r3 = ht(acc[h][3]*scv[h].w + shv[h].w);
      float p0 = fmaxf(r0, __shfl_xor(r0,1,64));
      float p1 = fmaxf(r1, __shfl_xor(r1,1,64));
      float p2 = fmaxf(r2, __shfl_xor(r2,1,64));
      float p3 = fmaxf(r3, __shfl_xor(r3,1,64));
      if((m&1)==0){
        float4 st = make_float4(p0,p1,p2,p3);
        *(float4*)&out3[(b*256 + pp)*64 + 32*hb + 16*h + 4*q] = st;
      }
    }
  }
}

// =============== k4: mean + concat rms + fc1 + ht + fc2 -> out[B,2] ======================
__global__ __launch_bounds__(256) void k4(const float* __restrict__ p3,
    const float* __restrict__ rms, const float* __restrict__ fc1w,
    const float* __restrict__ fc1b, const float* __restrict__ fc2w,
    const float* __restrict__ fc2b, float* __restrict__ out){
  __shared__ float part[256];
  __shared__ float feat[64];
  __shared__ float hbuf[32];
  const int b = blockIdx.x, tid = threadIdx.x;
  const int oc = tid & 63, grp = tid >> 6;
  const float* base = &p3[(b*256 + grp*64)*64 + oc];   // [pos][oc] layout
  float s = 0.f;
  #pragma unroll 8
  for(int j=0;j<64;++j) s += base[j*64];
  part[tid] = s;
  __syncthreads();
  if(tid < 64)
    feat[tid] = (part[tid]+part[64+tid]+part[128+tid]+part[192+tid])*(1.f/256.f);
  __syncthreads();
  if(tid < 32){
    float acc = fc1b[tid];
    const float* wv = &fc1w[tid*65];
    #pragma unroll
    for(int c = 0; c < 64; ++c) acc += wv[c]*feat[c];
    acc += wv[64]*rms[b];
    hbuf[tid] = ht(acc);
  }
  __syncthreads();
  if(tid < 2){
    float acc = fc2b[tid];
    const float* wv = &fc2w[tid*32];
    #pragma unroll
    for(int j = 0; j < 32; ++j) acc += wv[j]*hbuf[j];
    out[b*2 + tid] = acc;
  }
}

extern "C" void kernel_launch(void* const* d_in, const int* in_sizes, int n_in,
                              void* d_out, int out_size, void* d_ws, size_t ws_size,
                              hipStream_t stream){
  (void)in_sizes; (void)n_in; (void)out_size; (void)ws_size;
  const float* x    = (const float*)d_in[0];
  const float* rms  = (const float*)d_in[1];
  const float* w1   = (const float*)d_in[2];
  const float* g1   = (const float*)d_in[3];
  const float* b1   = (const float*)d_in[4];
  const float* m1   = (const float*)d_in[5];
  const float* v1   = (const float*)d_in[6];
  const float* w2   = (const float*)d_in[7];
  const float* g2   = (const float*)d_in[8];
  const float* b2   = (const float*)d_in[9];
  const float* m2   = (const float*)d_in[10];
  const float* v2   = (const float*)d_in[11];
  const float* w3   = (const float*)d_in[12];
  const float* g3   = (const float*)d_in[13];
  const float* b3   = (const float*)d_in[14];
  const float* m3   = (const float*)d_in[15];
  const float* v3   = (const float*)d_in[16];
  const float* fc1w = (const float*)d_in[17];
  const float* fc1b = (const float*)d_in[18];
  const float* fc2w = (const float*)d_in[19];
  const float* fc2b = (const float*)d_in[20];
  float* out  = (float*)d_out;

  // ws layout
  float*          out3  = (float*)d_ws;                     // 4,194,304 f32 (16 MB)
  unsigned short* out1T = (unsigned short*)(out3 + 4194304);// 16,777,216 bf16 (33.5 MB)
  unsigned short* out2T = out1T + 16777216;                 //  8,388,608 bf16 (16.8 MB)
  unsigned short* a1    = out2T + 8388608;                  //   512
  unsigned short* a2    = a1 + 512;                         //  5120
  unsigned short* a3    = a2 + 5120;                        // 10240
  float*          bnp   = (float*)(a3 + 10240);             //   224 f32 (16B-aligned)

  prep<<<1,    512, 0, stream>>>(w1, w2, w3, g1,b1,m1,v1, g2,b2,m2,v2, g3,b3,m3,v3,
                                 a1, a2, a3, bnp);
  k1<<<4096, 512, 0, stream>>>(x,     a1, bnp, out1T);
  k2<<<2048, 512, 0, stream>>>(out1T, a2, bnp, out2T);
  k3<<<1024, 512, 0, stream>>>(out2T, a3, bnp, out3);
  k4<<<256,  256, 0, stream>>>(out3, rms, fc1w, fc1b, fc2w, fc2b, out);
}

// Round 7
// 141.284 us; speedup vs baseline: 1.7117x; 1.1298x over previous
//
#include <hip/hip_runtime.h>

#define EPS 1e-5f

typedef float f32x4 __attribute__((ext_vector_type(4)));
typedef short s16x8 __attribute__((ext_vector_type(8)));

union FragU { uint4 u; s16x8 s; };

__device__ __forceinline__ float ht(float x){ return fminf(fmaxf(x,-1.f),1.f); }
__device__ __forceinline__ float sgn(float v){ return (v>0.f)?1.f:((v<0.f)?-1.f:0.f); }
__device__ __forceinline__ unsigned short f2bf(float f){
    unsigned int u = __builtin_bit_cast(unsigned int, f);
    u += 0x7FFFu + ((u>>16)&1u);                 // RNE to bf16
    return (unsigned short)(u>>16);
}

// =============== prep: A-fragments (bf16, MFMA layout) + BN scale/shift ===============
__global__ __launch_bounds__(512) void prep(
    const float* __restrict__ w1, const float* __restrict__ w2, const float* __restrict__ w3,
    const float* g1,const float* b1,const float* m1,const float* v1,
    const float* g2,const float* b2,const float* m2,const float* v2,
    const float* g3,const float* b3,const float* m3,const float* v3,
    unsigned short* __restrict__ a1, unsigned short* __restrict__ a2,
    unsigned short* __restrict__ a3, float* __restrict__ bn){
  const int t = threadIdx.x;
  if(t < 64){                                    // conv1: K=32 (k<17 real)
    int q = t>>4, m = t&15;
    #pragma unroll
    for(int j=0;j<8;++j){ int k = 8*q+j;
      a1[t*8+j] = f2bf((k<17)? w1[m*17+k] : 0.f); }
  }
  for(int e = t; e < 640; e += 512){             // conv2: [h2][c5][q4][m16], k-major K=160
    int m = e&15, q = (e>>4)&3, hc = e>>6, c = hc%5, h = hc/5;
    int oc = m + 16*h, k = 2*c + (q>>1);
    #pragma unroll
    for(int j=0;j<8;++j){ int ic = 8*(q&1)+j;
      a2[e*8+j] = f2bf((k<9)? sgn(w2[(oc*16+ic)*9+k]) : 0.f); }
  }
  for(int e = t; e < 1280; e += 512){            // conv3: [g4][c5][q4][m16], K=160
    int m = e&15, q = (e>>4)&3, gc = e>>6, c = gc%5, g = gc/5;
    int oc = m + 16*g;
    #pragma unroll
    for(int j=0;j<8;++j){ int ic = 8*q+j;
      a3[e*8+j] = f2bf(sgn(w3[(oc*32+ic)*5+c])); }
  }
  if(t<16){ float s = g1[t]*rsqrtf(v1[t]+EPS); bn[t]    = s; bn[16+t]  = b1[t]-m1[t]*s; }
  if(t<32){ float s = g2[t]*rsqrtf(v2[t]+EPS); bn[32+t] = s; bn[64+t]  = b2[t]-m2[t]*s; }
  if(t<64){ float s = g3[t]*rsqrtf(v3[t]+EPS); bn[96+t] = s; bn[160+t] = b3[t]-m3[t]*s; }
}

// =============== fused: x -> conv1 -> conv2 -> conv3 -> partial feature sums ===========
// Block owns 32 final pooled positions [Q0, Q0+32), Q0 = 32*(blockIdx&7). Grid = 256*8.
// All intermediates live in LDS; only x is read and 64 partial sums written.
__global__ __launch_bounds__(512, 4) void kfused(const float* __restrict__ x,
    const unsigned short* __restrict__ a1, const unsigned short* __restrict__ a2,
    const unsigned short* __restrict__ a3, const float* __restrict__ bn,
    float* __restrict__ partial){
  __shared__ __align__(16) unsigned short xs[2176];      // x[x0 .. x0+2176) bf16
  __shared__ __align__(16) unsigned short s1[552*24];    // [p1 local][16 oc], pad 24
  __shared__ __align__(16) unsigned short s2[132*40];    // [p2 local][32 oc], pad 40
  __shared__ float fws[8*32];
  const int b  = blockIdx.x >> 3;
  const int t  = blockIdx.x & 7;
  const int Q0 = 32*t;
  const int tid = threadIdx.x;
  const int lane = tid & 63, m = lane & 15, q = lane >> 4, w = tid >> 6;

  // ---- stage x -> xs ----
  const int x0 = 64*Q0 - 56;
  const float* xrow = &x[b*16384];
  for(int i = tid; i < 544; i += 512){
    int g0 = x0 + 4*i;
    float4 v = make_float4(0.f,0.f,0.f,0.f);
    if(g0 >= 0 && g0 <= 16380) v = *(const float4*)&xrow[g0];
    uint2 pk;
    pk.x = (unsigned)f2bf(v.x) | ((unsigned)f2bf(v.y)<<16);
    pk.y = (unsigned)f2bf(v.z) | ((unsigned)f2bf(v.w)<<16);
    *(uint2*)&xs[4*i] = pk;
  }
  FragU af1; af1.u = *(const uint4*)&a1[(q*16+m)*8];
  const float4 sc1 = *(const float4*)&bn[4*q];
  const float4 sh1 = *(const float4*)&bn[16+4*q];
  __syncthreads();

  // ---- stage 1: conv1 on 1072 pre-pool columns (67 tiles) -> s1[536][16] ----
  const unsigned* X32 = (const unsigned*)xs;
  for(int it = 0; it < 9; ++it){
    int tile = it*8 + w;                         // wave-uniform guard
    if(tile < 67){
      int nl = tile*16 + m;
      int d = nl + 4*q;
      FragU bf;
      bf.u.x = X32[d]; bf.u.y = X32[d+1]; bf.u.z = X32[d+2]; bf.u.w = X32[d+3];
      f32x4 acc = {0.f,0.f,0.f,0.f};
      acc = __builtin_amdgcn_mfma_f32_16x16x32_bf16(af1.s, bf.s, acc, 0,0,0);
      float r0 = ht(acc[0]*sc1.x + sh1.x);
      float r1 = ht(acc[1]*sc1.y + sh1.y);
      float r2 = ht(acc[2]*sc1.z + sh1.z);
      float r3 = ht(acc[3]*sc1.w + sh1.w);
      float p0 = fmaxf(r0, __shfl_xor(r0,1,64));
      float p1 = fmaxf(r1, __shfl_xor(r1,1,64));
      float p2 = fmaxf(r2, __shfl_xor(r2,1,64));
      float p3 = fmaxf(r3, __shfl_xor(r3,1,64));
      if((m&1)==0){
        int ppl = nl >> 1;
        uint2 pk;
        pk.x = (unsigned)f2bf(p0) | ((unsigned)f2bf(p1)<<16);
        pk.y = (unsigned)f2bf(p2) | ((unsigned)f2bf(p3)<<16);
        *(uint2*)&s1[ppl*24 + 4*q] = pk;
      }
    }
  }
  __syncthreads();

  // ---- stage 2: conv2 on 264 pre-pool columns (17 tiles) -> s2[132][32] ----
  FragU af2[2][5];
  #pragma unroll
  for(int h=0;h<2;++h)
    #pragma unroll
    for(int c=0;c<5;++c)
      af2[h][c].u = *(const uint4*)&a2[(((h*5+c)*4+q)*16+m)*8];
  float4 sc2[2], sh2[2];
  #pragma unroll
  for(int h=0;h<2;++h){
    sc2[h] = *(const float4*)&bn[32 + 16*h + 4*q];
    sh2[h] = *(const float4*)&bn[64 + 16*h + 4*q];
  }
  for(int it = 0; it < 3; ++it){
    int tile = it*8 + w;                         // wave-uniform guard
    if(tile < 17){
      int nl = tile*16 + m;
      f32x4 acc[2] = {{0.f,0.f,0.f,0.f},{0.f,0.f,0.f,0.f}};
      #pragma unroll
      for(int c=0;c<5;++c){
        int row = 2*nl + 2*c + (q>>1);
        FragU bf; bf.u = *(const uint4*)&s1[row*24 + 8*(q&1)];
        acc[0] = __builtin_amdgcn_mfma_f32_16x16x32_bf16(af2[0][c].s, bf.s, acc[0],0,0,0);
        acc[1] = __builtin_amdgcn_mfma_f32_16x16x32_bf16(af2[1][c].s, bf.s, acc[1],0,0,0);
      }
      #pragma unroll
      for(int h=0;h<2;++h){
        float r0 = ht(acc[h][0]*sc2[h].x + sh2[h].x);
        float r1 = ht(acc[h][1]*sc2[h].y + sh2[h].y);
        float r2 = ht(acc[h][2]*sc2[h].z + sh2[h].z);
        float r3 = ht(acc[h][3]*sc2[h].w + sh2[h].w);
        float p0 = fmaxf(r0, __shfl_xor(r0,1,64));
        float p1 = fmaxf(r1, __shfl_xor(r1,1,64));
        float p2 = fmaxf(r2, __shfl_xor(r2,1,64));
        float p3 = fmaxf(r3, __shfl_xor(r3,1,64));
        if((m&1)==0 && nl < 264){
          int ppl = nl >> 1;
          uint2 pk;
          pk.x = (unsigned)f2bf(p0) | ((unsigned)f2bf(p1)<<16);
          pk.y = (unsigned)f2bf(p2) | ((unsigned)f2bf(p3)<<16);
          *(uint2*)&s2[ppl*40 + 16*h + 4*q] = pk;
        }
      }
    }
  }
  __syncthreads();

  // ---- stage 3: conv3 on 64 pre-pool columns; wave = (tile w&3, oc-pair w>>2) ----
  const int gw = w >> 2, tw = w & 3;
  FragU af3[2][5];
  #pragma unroll
  for(int gl=0;gl<2;++gl)
    #pragma unroll
    for(int c=0;c<5;++c)
      af3[gl][c].u = *(const uint4*)&a3[((((2*gw+gl)*5+c)*4+q)*16+m)*8];
  float4 sc3[2], sh3[2];
  #pragma unroll
  for(int gl=0;gl<2;++gl){
    sc3[gl] = *(const float4*)&bn[96  + 16*(2*gw+gl) + 4*q];
    sh3[gl] = *(const float4*)&bn[160 + 16*(2*gw+gl) + 4*q];
  }
  {
    int nl = tw*16 + m;
    f32x4 acc[2] = {{0.f,0.f,0.f,0.f},{0.f,0.f,0.f,0.f}};
    #pragma unroll
    for(int c=0;c<5;++c){
      int row = 2*nl + c;
      FragU bf; bf.u = *(const uint4*)&s2[row*40 + 8*q];
      acc[0] = __builtin_amdgcn_mfma_f32_16x16x32_bf16(af3[0][c].s, bf.s, acc[0],0,0,0);
      acc[1] = __builtin_amdgcn_mfma_f32_16x16x32_bf16(af3[1][c].s, bf.s, acc[1],0,0,0);
    }
    #pragma unroll
    for(int gl=0;gl<2;++gl){
      float r0 = ht(acc[gl][0]*sc3[gl].x + sh3[gl].x);
      float r1 = ht(acc[gl][1]*sc3[gl].y + sh3[gl].y);
      float r2 = ht(acc[gl][2]*sc3[gl].z + sh3[gl].z);
      float r3 = ht(acc[gl][3]*sc3[gl].w + sh3[gl].w);
      float p0 = fmaxf(r0, __shfl_xor(r0,1,64));
      float p1 = fmaxf(r1, __shfl_xor(r1,1,64));
      float p2 = fmaxf(r2, __shfl_xor(r2,1,64));
      float p3 = fmaxf(r3, __shfl_xor(r3,1,64));
      // xor-2/4/8 tree stays within one lane-parity class: each of the tile's 8
      // pooled values lives in exactly one even lane -> summed ONCE (no x0.5!).
      float s0 = p0, s1v = p1, s2v = p2, s3 = p3;
      s0 += __shfl_xor(s0,2,64); s0 += __shfl_xor(s0,4,64); s0 += __shfl_xor(s0,8,64);
      s1v += __shfl_xor(s1v,2,64); s1v += __shfl_xor(s1v,4,64); s1v += __shfl_xor(s1v,8,64);
      s2v += __shfl_xor(s2v,2,64); s2v += __shfl_xor(s2v,4,64); s2v += __shfl_xor(s2v,8,64);
      s3 += __shfl_xor(s3,2,64); s3 += __shfl_xor(s3,4,64); s3 += __shfl_xor(s3,8,64);
      if(m == 0)
        *(float4*)&fws[w*32 + 16*gl + 4*q] = make_float4(s0,s1v,s2v,s3);
    }
  }
  __syncthreads();
  if(tid < 64){
    int oc = tid;
    int wb = (oc >> 5) * 4;                       // waves 0-3: oc 0-31, waves 4-7: oc 32-63
    int ocl = oc & 31;
    float sum = fws[wb*32+ocl] + fws[(wb+1)*32+ocl] + fws[(wb+2)*32+ocl] + fws[(wb+3)*32+ocl];
    partial[(b*8 + t)*64 + oc] = sum;             // R6 bug was 0.5f*sum
  }
}

// =============== kfc: reduce partials + fc1 + ht + fc2 -> out[B,2] ======================
__global__ __launch_bounds__(64) void kfc(const float* __restrict__ partial,
    const float* __restrict__ rms, const float* __restrict__ fc1w,
    const float* __restrict__ fc1b, const float* __restrict__ fc2w,
    const float* __restrict__ fc2b, float* __restrict__ out){
  __shared__ float feat[64];
  __shared__ float hbuf[32];
  const int b = blockIdx.x, tid = threadIdx.x;
  float s = 0.f;
  #pragma unroll
  for(int t = 0; t < 8; ++t) s += partial[(b*8 + t)*64 + tid];
  feat[tid] = s * (1.f/256.f);
  __syncthreads();
  if(tid < 32){
    float acc = fc1b[tid];
    const float* wv = &fc1w[tid*65];
    #pragma unroll
    for(int c = 0; c < 64; ++c) acc += wv[c]*feat[c];
    acc += wv[64]*rms[b];
    hbuf[tid] = ht(acc);
  }
  __syncthreads();
  if(tid < 2){
    float acc = fc2b[tid];
    const float* wv = &fc2w[tid*32];
    #pragma unroll
    for(int j = 0; j < 32; ++j) acc += wv[j]*hbuf[j];
    out[b*2 + tid] = acc;
  }
}

extern "C" void kernel_launch(void* const* d_in, const int* in_sizes, int n_in,
                              void* d_out, int out_size, void* d_ws, size_t ws_size,
                              hipStream_t stream){
  (void)in_sizes; (void)n_in; (void)out_size; (void)ws_size;
  const float* x    = (const float*)d_in[0];
  const float* rms  = (const float*)d_in[1];
  const float* w1   = (const float*)d_in[2];
  const float* g1   = (const float*)d_in[3];
  const float* b1   = (const float*)d_in[4];
  const float* m1   = (const float*)d_in[5];
  const float* v1   = (const float*)d_in[6];
  const float* w2   = (const float*)d_in[7];
  const float* g2   = (const float*)d_in[8];
  const float* b2   = (const float*)d_in[9];
  const float* m2   = (const float*)d_in[10];
  const float* v2   = (const float*)d_in[11];
  const float* w3   = (const float*)d_in[12];
  const float* g3   = (const float*)d_in[13];
  const float* b3   = (const float*)d_in[14];
  const float* m3   = (const float*)d_in[15];
  const float* v3   = (const float*)d_in[16];
  const float* fc1w = (const float*)d_in[17];
  const float* fc1b = (const float*)d_in[18];
  const float* fc2w = (const float*)d_in[19];
  const float* fc2b = (const float*)d_in[20];
  float* out  = (float*)d_out;

  // ws layout
  float*          partial = (float*)d_ws;                      // 256*8*64 f32 (512 KB)
  unsigned short* a1  = (unsigned short*)(partial + 131072);   //   512 bf16
  unsigned short* a2  = a1 + 512;                              //  5120 bf16
  unsigned short* a3  = a2 + 5120;                             // 10240 bf16
  float*          bnp = (float*)(a3 + 10240);                  //   224 f32 (16B aligned)

  prep<<<1,    512, 0, stream>>>(w1, w2, w3, g1,b1,m1,v1, g2,b2,m2,v2, g3,b3,m3,v3,
                                 a1, a2, a3, bnp);
  kfused<<<2048, 512, 0, stream>>>(x, a1, a2, a3, bnp, partial);
  kfc<<<256, 64, 0, stream>>>(partial, rms, fc1w, fc1b, fc2w, fc2b, out);
}